// Round 3
// baseline (5739.262 us; speedup 1.0000x reference)
//
#include <hip/hip_runtime.h>
#include <hip/hip_bf16.h>

#define B_ 1024
#define T_ 64
#define FEAT_ 1024
#define TENC_ 256
#define MAN_ 128
#define HID_ 2048
#define NG_ 8192   /* 4*HID */
#define IND_ 1408

typedef __attribute__((ext_vector_type(8))) short short8;
typedef __attribute__((ext_vector_type(4))) float f32x4;

typedef const __attribute__((address_space(1))) void as1_cvoid;
typedef __attribute__((address_space(3))) void as3_void;

static __device__ __forceinline__ float sigmoidf_(float x) {
  return 1.0f / (1.0f + __expf(-x));
}
static __device__ __forceinline__ float tanh_fast(float x) {
  return 1.0f - 2.0f / (__expf(2.0f * x) + 1.0f);
}
static __device__ __forceinline__ unsigned short f2b(float x) {
  __hip_bfloat16 h = __float2bfloat16(x);
  return *reinterpret_cast<unsigned short*>(&h);
}
static __device__ __forceinline__ float b2f(unsigned short u) {
  unsigned int v = ((unsigned int)u) << 16;
  return *reinterpret_cast<float*>(&v);
}

// gate permutation: new col p -> original gate-matrix row
// gate = (p>>4)&3, h = (p>>7)*32 + ((p>>6)&1)*16 + (p&15)
static __device__ __forceinline__ int gate_perm(int p) {
  int h = ((p >> 7) << 5) + (((p >> 6) & 1) << 4) + (p & 15);
  int gate = (p >> 4) & 3;
  return gate * HID_ + h;
}

__device__ __forceinline__ void gload16(const unsigned short* g, unsigned short* l) {
  __builtin_amdgcn_global_load_lds((as1_cvoid*)g, (as3_void*)l, 16, 0, 0);
}

// ---------------- small prep kernels ----------------

__global__ void zero_u32(unsigned int* p, long n) {
  long i = (long)blockIdx.x * blockDim.x + threadIdx.x;
  if (i < n) p[i] = 0u;
}

// fp32 (rows x cols slice) -> contiguous bf16
__global__ void pack_bf16(const float* __restrict__ src, long ld, long off,
                          unsigned short* __restrict__ dst, long cols) {
  long c = ((long)blockIdx.x * blockDim.x + threadIdx.x) * 4;
  if (c >= cols) return;
  long r = blockIdx.y;
  float4 v = *reinterpret_cast<const float4*>(&src[r * ld + off + c]);
  ushort4 o;
  o.x = f2b(v.x); o.y = f2b(v.y); o.z = f2b(v.z); o.w = f2b(v.w);
  *reinterpret_cast<ushort4*>(&dst[r * cols + c]) = o;
}

// one-pass W_ih split: row rd (gate-permuted from src), cols -> Wx | Wy | Wte (bf16)
__global__ void pack_wih(const float* __restrict__ W_ih,
                         unsigned short* __restrict__ Wx,
                         unsigned short* __restrict__ Wy,
                         unsigned short* __restrict__ Wte) {
  int c = (blockIdx.x * 256 + threadIdx.x) * 4;
  if (c >= IND_) return;
  long rd = blockIdx.y;
  long rs = gate_perm((int)rd);
  float4 v = *reinterpret_cast<const float4*>(&W_ih[rs * IND_ + c]);
  ushort4 o;
  o.x = f2b(v.x); o.y = f2b(v.y); o.z = f2b(v.z); o.w = f2b(v.w);
  if (c < FEAT_) {
    *reinterpret_cast<ushort4*>(&Wx[rd * FEAT_ + c]) = o;
  } else if (c < FEAT_ + MAN_) {
    *reinterpret_cast<ushort4*>(&Wy[rd * MAN_ + (c - FEAT_)]) = o;
  } else {
    *reinterpret_cast<ushort4*>(&Wte[rd * TENC_ + (c - FEAT_ - MAN_)]) = o;
  }
}

// WmuT[n][m] = bf16(W_mu[m][n]);  W_mu: (MAN_, HID_)
__global__ void transpose_to_bf16(const float* __restrict__ src, unsigned short* __restrict__ dst) {
  int i = blockIdx.x * 256 + threadIdx.x;       // over HID_*MAN_
  int n = i >> 7, m = i & 127;
  dst[i] = f2b(src[(long)m * HID_ + n]);
}

// permuted: bvec2[p] = (b_ih + b_hh + b_mu@Wy^T)[gate_perm(p)];  nbm[p] = -(b_mu@Wy^T)[gate_perm(p)]
__global__ void bias_prep(const float* __restrict__ W_ih, const float* __restrict__ b_ih,
                          const float* __restrict__ b_hh, const float* __restrict__ b_mu,
                          float* __restrict__ bvec2, float* __restrict__ nbm) {
  int p = blockIdx.x * 256 + threadIdx.x;
  if (p >= NG_) return;
  int g = gate_perm(p);
  const float* wy = &W_ih[(long)g * IND_ + FEAT_];
  float s = 0.f;
  #pragma unroll 8
  for (int m = 0; m < MAN_; ++m) s += b_mu[m] * wy[m];
  bvec2[p] = b_ih[g] + b_hh[g] + s;
  nbm[p] = -s;
}

__global__ void out_t0(const float* __restrict__ y0, float* __restrict__ out) {
  int i = blockIdx.x * 256 + threadIdx.x;       // over B_*MAN_
  int b = i >> 7, m = i & 127;
  out[(long)b * (T_ * MAN_) + m] = y0[i];
}

// ---------------- generic bf16 MFMA GEMM: C = A @ W^T (+bias[col]) (+addmat) ----------
// A: M x K via two K-regions (boundary K1). W: N x K via two regions, bf16 row-major.
// Double-buffered LDS (2-phase pipeline: stage k+1 in flight under compute of k),
// one barrier per K-tile, bijective XCD-aware block swizzle.
// SMODE: 0 = fp32 store at out[row*ldo+col]; 1 = bf16 store; 2 = decoder scatter
//        (row -> b=row&1023, t=(row>>10)+1; out[b*T*MAN + t*MAN + col], fp32);
//        3 = fused LSTM cell (gate-permuted cols; updates cstate fp32, writes hout bf16).
// AMODE: 0 = none; 1 = fp32 addmat[row*N+col]; 2 = bf16 addmat[row*N+col];
//        3 = fp32 addmat[gate_perm(row)*N+col].
template<int SMODE, int AMODE>
__global__ __launch_bounds__(256, 2)
void gemm_bt(const unsigned short* __restrict__ A1, long lda1,
             const unsigned short* __restrict__ A2, long lda2, int K1,
             const unsigned short* __restrict__ W1, const unsigned short* __restrict__ W2,
             int N, int K,
             const float* __restrict__ bias, const void* __restrict__ addmat,
             void* __restrict__ outp, long ldo,
             float* __restrict__ cstate, unsigned short* __restrict__ hout)
{
  __shared__ unsigned short As[2][128 * 64];
  __shared__ unsigned short Bs[2][128 * 64];
  const int tid = threadIdx.x, lane = tid & 63, wave = tid >> 6;

  // bijective XCD swizzle (m204): each XCD owns a contiguous chunk of bn-panels
  const int nwg = (int)(gridDim.x * gridDim.y);
  const int flat = (int)(blockIdx.y * gridDim.x + blockIdx.x);
  const int q = nwg >> 3, r = nwg & 7;
  const int xcd = flat & 7, idx = flat >> 3;
  const int sw = (xcd < r ? xcd * (q + 1) : r * (q + 1) + (xcd - r) * q) + idx;
  const long bm = sw % (int)gridDim.x, bn = sw / (int)gridDim.x;

  f32x4 acc[4][4] = {};

  const int nkt = K >> 6;
  const int wm = wave >> 1, wn = wave & 1;
  const int lr = lane & 15, lq = lane >> 4;

  auto stage = [&](int kt, int buf) {
    const int k0 = kt << 6;
    const unsigned short* Ab; long lda; const unsigned short* Wb; long ldw; int ko;
    if (k0 < K1) { Ab = A1; lda = lda1; Wb = W1; ldw = K1;      ko = k0; }
    else         { Ab = A2; lda = lda2; Wb = W2; ldw = K - K1;  ko = k0 - K1; }
    #pragma unroll
    for (int it = 0; it < 4; ++it) {
      const int c0 = it * 256 + wave * 64;
      const int c = c0 + lane;
      const int row = c >> 3, sub = c & 7;
      gload16(Ab + (bm * 128 + row) * lda + ko + sub * 8, &As[buf][c0 * 8]);
      gload16(Wb + (bn * 128 + row) * ldw + ko + sub * 8, &Bs[buf][c0 * 8]);
    }
  };

  stage(0, 0);
  int cur = 0;
  for (int kt = 0; kt < nkt; ++kt) {
    __syncthreads();                    // drains vmcnt for buf[cur]'s stage
    if (kt + 1 < nkt) stage(kt + 1, cur ^ 1);   // prefetch under compute
    #pragma unroll
    for (int kk = 0; kk < 2; ++kk) {
      short8 av[4], bv[4];
      const int lk = kk * 32 + lq * 8;
      #pragma unroll
      for (int m = 0; m < 4; ++m)
        av[m] = *reinterpret_cast<const short8*>(&As[cur][(wm * 64 + m * 16 + lr) * 64 + lk]);
      #pragma unroll
      for (int n = 0; n < 4; ++n)
        bv[n] = *reinterpret_cast<const short8*>(&Bs[cur][(wn * 64 + n * 16 + lr) * 64 + lk]);
      #pragma unroll
      for (int m = 0; m < 4; ++m)
        #pragma unroll
        for (int n = 0; n < 4; ++n)
          acc[m][n] = __builtin_amdgcn_mfma_f32_16x16x32_bf16(av[m], bv[n], acc[m][n], 0, 0, 0);
    }
    cur ^= 1;
  }

  if constexpr (SMODE == 3) {
    // fused LSTM cell: thread's n=0..3 fragments are i,f,g,o for h = bn*32+wn*16+lr
    const int hcol = (int)bn * 32 + wn * 16 + lr;
    const long colbase = bn * 128 + wn * 64 + lr;
    #pragma unroll
    for (int m = 0; m < 4; ++m) {
      #pragma unroll
      for (int r2 = 0; r2 < 4; ++r2) {
        const long row = bm * 128 + wm * 64 + m * 16 + lq * 4 + r2;
        float gi = acc[m][0][r2], gf = acc[m][1][r2], gg = acc[m][2][r2], go = acc[m][3][r2];
        const unsigned short* am = (const unsigned short*)addmat;
        const long ab = row * (long)N + colbase;
        gi += b2f(am[ab]);
        gf += b2f(am[ab + 16]);
        gg += b2f(am[ab + 32]);
        go += b2f(am[ab + 48]);
        const long ci = row * HID_ + hcol;
        float c = cstate[ci];
        c = sigmoidf_(gf) * c + sigmoidf_(gi) * tanh_fast(gg);
        cstate[ci] = c;
        hout[ci] = f2b(sigmoidf_(go) * tanh_fast(c));
      }
    }
    return;
  }

  // standard epilogues
  #pragma unroll
  for (int m = 0; m < 4; ++m) {
    #pragma unroll
    for (int n = 0; n < 4; ++n) {
      const long col = bn * 128 + wn * 64 + n * 16 + lr;
      const float bvv = bias ? bias[col] : 0.0f;
      #pragma unroll
      for (int r2 = 0; r2 < 4; ++r2) {
        const long row = bm * 128 + wm * 64 + m * 16 + lq * 4 + r2;
        float v = acc[m][n][r2] + bvv;
        if constexpr (AMODE == 1) v += ((const float*)addmat)[row * (long)N + col];
        if constexpr (AMODE == 2) v += b2f(((const unsigned short*)addmat)[row * (long)N + col]);
        if constexpr (AMODE == 3) v += ((const float*)addmat)[(long)gate_perm((int)row) * N + col];
        if constexpr (SMODE == 0) {
          reinterpret_cast<float*>(outp)[row * ldo + col] = v;
        } else if constexpr (SMODE == 1) {
          reinterpret_cast<unsigned short*>(outp)[row * ldo + col] = f2b(v);
        } else {
          const long bb = row & 1023, tt = (row >> 10) + 1;
          reinterpret_cast<float*>(outp)[bb * (T_ * MAN_) + tt * MAN_ + col] = v;
        }
      }
    }
  }
}

// ---------------- launcher ----------------
extern "C" void kernel_launch(void* const* d_in, const int* in_sizes, int n_in,
                              void* d_out, int out_size, void* d_ws, size_t ws_size,
                              hipStream_t stream) {
  const float* input_repr = (const float*)d_in[0];
  const float* time_enc   = (const float*)d_in[1];
  const float* y0         = (const float*)d_in[2];
  const float* W_ih       = (const float*)d_in[3];
  const float* b_ih       = (const float*)d_in[4];
  const float* b_hh       = (const float*)d_in[6];
  const float* W_hh       = (const float*)d_in[5];
  const float* W_mu       = (const float*)d_in[7];
  const float* b_mu       = (const float*)d_in[8];
  float* out = (float*)d_out;

  char* ws = (char*)d_ws;
  auto alloc = [&](size_t bytes) {
    char* p = ws; ws += (bytes + 255) & ~(size_t)255; return p;
  };
  unsigned short* Xbf    = (unsigned short*)alloc((size_t)B_ * T_ * FEAT_ * 2);   // 134 MB
  unsigned short* hstore = (unsigned short*)alloc((size_t)T_ * B_ * HID_ * 2);    // 268 MB
  float*  cst   = (float*)alloc((size_t)B_ * HID_ * 4);                           // 8.4 MB
  unsigned short* TB2 = (unsigned short*)alloc((size_t)B_ * NG_ * 2);             // 16.8 MB (bf16, perm cols)
  unsigned short* TB1 = (unsigned short*)alloc((size_t)B_ * NG_ * 2);             // 16.8 MB
  unsigned short* Whhf  = (unsigned short*)alloc((size_t)NG_ * HID_ * 2);         // 33.5 MB (perm rows)
  unsigned short* Wxbf  = (unsigned short*)alloc((size_t)NG_ * FEAT_ * 2);        // 16.8 MB (perm rows)
  unsigned short* Wybf  = (unsigned short*)alloc((size_t)NG_ * MAN_ * 2);         // (perm rows)
  unsigned short* Wtebf = (unsigned short*)alloc((size_t)NG_ * TENC_ * 2);        // (perm rows)
  unsigned short* WmuT  = (unsigned short*)alloc((size_t)HID_ * MAN_ * 2);
  unsigned short* Wmubf = (unsigned short*)alloc((size_t)MAN_ * HID_ * 2);
  unsigned short* tebf  = (unsigned short*)alloc((size_t)B_ * TENC_ * 2);
  unsigned short* y0bf  = (unsigned short*)alloc((size_t)B_ * MAN_ * 2);
  float* bvec2 = (float*)alloc(NG_ * 4);
  float* nbm   = (float*)alloc(NG_ * 4);

  // --- conversions / preps (all parallel work) ---
  pack_bf16<<<dim3(64, B_), 256, 0, stream>>>(input_repr, (long)T_ * FEAT_, 0, Xbf, (long)T_ * FEAT_);
  pack_wih<<<dim3(2, NG_), 256, 0, stream>>>(W_ih, Wxbf, Wybf, Wtebf);
  pack_bf16<<<dim3(2, MAN_), 256, 0, stream>>>(W_mu, HID_, 0, Wmubf, HID_);
  pack_bf16<<<dim3(1, B_), 256, 0, stream>>>(time_enc, TENC_, 0, tebf, TENC_);
  pack_bf16<<<dim3(1, B_), 256, 0, stream>>>(y0, MAN_, 0, y0bf, MAN_);
  transpose_to_bf16<<<1024, 256, 0, stream>>>(W_mu, WmuT);
  bias_prep<<<NG_ / 256, 256, 0, stream>>>(W_ih, b_ih, b_hh, b_mu, bvec2, nbm);
  zero_u32<<<(B_ * HID_ / 2 + 255) / 256, 256, 0, stream>>>((unsigned int*)hstore, (long)B_ * HID_ / 2); // h0 = 0
  zero_u32<<<(B_ * HID_ + 255) / 256, 256, 0, stream>>>((unsigned int*)cst, (long)B_ * HID_);            // c0 = 0
  out_t0<<<B_ * MAN_ / 256, 256, 0, stream>>>(y0, out);

  // Whhf = perm(W_hh) + permWy @ W_mu   (bf16, rows permuted)   M=NG_, N=HID_, K=MAN_
  gemm_bt<1, 3><<<dim3(NG_ / 128, HID_ / 128), 256, 0, stream>>>(
      Wybf, MAN_, Wybf, MAN_, MAN_, WmuT, WmuT, HID_, MAN_,
      nullptr, W_hh, Whhf, HID_, nullptr, nullptr);
  // TB2 = te @ permWte^T + permuted(b_ih + b_hh + b_mu@Wy^T)    M=B_, N=NG_, K=TENC_ (bf16 out)
  gemm_bt<1, 0><<<dim3(B_ / 128, NG_ / 128), 256, 0, stream>>>(
      tebf, TENC_, tebf, TENC_, TENC_, Wtebf, Wtebf, NG_, TENC_,
      bvec2, nullptr, TB2, NG_, nullptr, nullptr);
  // TB1 = y0 @ permWy^T + TB2 - permuted(b_mu@Wy^T)             M=B_, N=NG_, K=MAN_ (bf16 out)
  gemm_bt<1, 2><<<dim3(B_ / 128, NG_ / 128), 256, 0, stream>>>(
      y0bf, MAN_, y0bf, MAN_, MAN_, Wybf, Wybf, NG_, MAN_,
      nbm, TB2, TB1, NG_, nullptr, nullptr);

  // --- recurrence: 63 steps, each ONE fused launch: gates GEMM (K=3072) + in-epilogue cell ---
  for (int t = 1; t < T_; ++t) {
    const unsigned short* A1 = Xbf + (long)t * FEAT_;                 // x_t, row stride T*FEAT
    const unsigned short* A2 = hstore + (long)(t - 1) * B_ * HID_;    // h_{t-1}
    gemm_bt<3, 2><<<dim3(B_ / 128, NG_ / 128), 256, 0, stream>>>(
        A1, (long)T_ * FEAT_, A2, HID_, FEAT_,
        Wxbf, Whhf, NG_, FEAT_ + HID_,
        nullptr, (t == 1 ? TB1 : TB2), nullptr, 0,
        cst, hstore + (long)t * B_ * HID_);
  }

  // --- all outputs y_t = h_t @ W_mu^T + b_mu in one GEMM, scattered into (B,T,MAN) ---
  gemm_bt<2, 0><<<dim3((T_ - 1) * B_ / 128, MAN_ / 128), 256, 0, stream>>>(
      hstore + (long)B_ * HID_, HID_, hstore + (long)B_ * HID_, HID_, HID_,
      Wmubf, Wmubf, MAN_, HID_,
      b_mu, nullptr, out, 0, nullptr, nullptr);
}

// Round 4
// 5469.230 us; speedup vs baseline: 1.0494x; 1.0494x over previous
//
#include <hip/hip_runtime.h>
#include <hip/hip_bf16.h>

#define B_ 1024
#define T_ 64
#define FEAT_ 1024
#define TENC_ 256
#define MAN_ 128
#define HID_ 2048
#define NG_ 8192   /* 4*HID */
#define IND_ 1408
#define CHUNK_ 21  /* 63 = 3 * 21 steps of xg precompute */

typedef __attribute__((ext_vector_type(8))) short short8;
typedef __attribute__((ext_vector_type(4))) float f32x4;

typedef const __attribute__((address_space(1))) void as1_cvoid;
typedef __attribute__((address_space(3))) void as3_void;

static __device__ __forceinline__ float sigmoidf_(float x) {
  return 1.0f / (1.0f + __expf(-x));
}
static __device__ __forceinline__ float tanh_fast(float x) {
  return 1.0f - 2.0f / (__expf(2.0f * x) + 1.0f);
}
static __device__ __forceinline__ unsigned short f2b(float x) {
  __hip_bfloat16 h = __float2bfloat16(x);
  return *reinterpret_cast<unsigned short*>(&h);
}
static __device__ __forceinline__ float b2f(unsigned short u) {
  unsigned int v = ((unsigned int)u) << 16;
  return *reinterpret_cast<float*>(&v);
}

// gate permutation: new col p -> original gate-matrix row
// gate = (p>>4)&3, h = (p>>7)*32 + ((p>>6)&1)*16 + (p&15)
static __device__ __forceinline__ int gate_perm(int p) {
  int h = ((p >> 7) << 5) + (((p >> 6) & 1) << 4) + (p & 15);
  int gate = (p >> 4) & 3;
  return gate * HID_ + h;
}

__device__ __forceinline__ void gload16(const unsigned short* g, unsigned short* l) {
  __builtin_amdgcn_global_load_lds((as1_cvoid*)g, (as3_void*)l, 16, 0, 0);
}

// ---------------- small prep kernels ----------------

__global__ void zero_u32(unsigned int* p, long n) {
  long i = (long)blockIdx.x * blockDim.x + threadIdx.x;
  if (i < n) p[i] = 0u;
}

// X [b][t][f] fp32 -> Xtm [t][b][f] bf16
__global__ void pack_x_tm(const float* __restrict__ src, unsigned short* __restrict__ dst) {
  int c = threadIdx.x * 4;
  int bt = blockIdx.x;
  int b = bt >> 6, t = bt & 63;
  float4 v = *reinterpret_cast<const float4*>(&src[((long)b * T_ + t) * FEAT_ + c]);
  ushort4 o;
  o.x = f2b(v.x); o.y = f2b(v.y); o.z = f2b(v.z); o.w = f2b(v.w);
  *reinterpret_cast<ushort4*>(&dst[((long)t * B_ + b) * FEAT_ + c]) = o;
}

// fp32 (rows x cols slice) -> contiguous bf16
__global__ void pack_bf16(const float* __restrict__ src, long ld, long off,
                          unsigned short* __restrict__ dst, long cols) {
  long c = ((long)blockIdx.x * blockDim.x + threadIdx.x) * 4;
  if (c >= cols) return;
  long r = blockIdx.y;
  float4 v = *reinterpret_cast<const float4*>(&src[r * ld + off + c]);
  ushort4 o;
  o.x = f2b(v.x); o.y = f2b(v.y); o.z = f2b(v.z); o.w = f2b(v.w);
  *reinterpret_cast<ushort4*>(&dst[r * cols + c]) = o;
}

// one-pass W_ih split: row rd (gate-permuted from src), cols -> Wx | Wy | Wte (bf16)
__global__ void pack_wih(const float* __restrict__ W_ih,
                         unsigned short* __restrict__ Wx,
                         unsigned short* __restrict__ Wy,
                         unsigned short* __restrict__ Wte) {
  int c = (blockIdx.x * 256 + threadIdx.x) * 4;
  if (c >= IND_) return;
  long rd = blockIdx.y;
  long rs = gate_perm((int)rd);
  float4 v = *reinterpret_cast<const float4*>(&W_ih[rs * IND_ + c]);
  ushort4 o;
  o.x = f2b(v.x); o.y = f2b(v.y); o.z = f2b(v.z); o.w = f2b(v.w);
  if (c < FEAT_) {
    *reinterpret_cast<ushort4*>(&Wx[rd * FEAT_ + c]) = o;
  } else if (c < FEAT_ + MAN_) {
    *reinterpret_cast<ushort4*>(&Wy[rd * MAN_ + (c - FEAT_)]) = o;
  } else {
    *reinterpret_cast<ushort4*>(&Wte[rd * TENC_ + (c - FEAT_ - MAN_)]) = o;
  }
}

// WmuT[n][m] = bf16(W_mu[m][n]);  W_mu: (MAN_, HID_)
__global__ void transpose_to_bf16(const float* __restrict__ src, unsigned short* __restrict__ dst) {
  int i = blockIdx.x * 256 + threadIdx.x;       // over HID_*MAN_
  int n = i >> 7, m = i & 127;
  dst[i] = f2b(src[(long)m * HID_ + n]);
}

// permuted: bvec2[p] = (b_ih + b_hh + b_mu@Wy^T)[gate_perm(p)];  nbm[p] = -(b_mu@Wy^T)[gate_perm(p)]
__global__ void bias_prep(const float* __restrict__ W_ih, const float* __restrict__ b_ih,
                          const float* __restrict__ b_hh, const float* __restrict__ b_mu,
                          float* __restrict__ bvec2, float* __restrict__ nbm) {
  int p = blockIdx.x * 256 + threadIdx.x;
  if (p >= NG_) return;
  int g = gate_perm(p);
  const float* wy = &W_ih[(long)g * IND_ + FEAT_];
  float s = 0.f;
  #pragma unroll 8
  for (int m = 0; m < MAN_; ++m) s += b_mu[m] * wy[m];
  bvec2[p] = b_ih[g] + b_hh[g] + s;
  nbm[p] = -s;
}

__global__ void out_t0(const float* __restrict__ y0, float* __restrict__ out) {
  int i = blockIdx.x * 256 + threadIdx.x;       // over B_*MAN_
  int b = i >> 7, m = i & 127;
  out[(long)b * (T_ * MAN_) + m] = y0[i];
}

// ---------------- generic bf16 MFMA GEMM: C = A @ W^T (+bias[col]) (+addmat) ----------
// A: M x K via two K-regions (boundary K1). W: N x K via two regions, bf16 row-major.
// R2-proven structure: single LDS buffer, two barriers per K-tile, no swizzle.
// SMODE: 0 = fp32 store at out[row*ldo+col]; 1 = bf16 store; 2 = decoder scatter
//        (row -> b=row&1023, t=(row>>10)+1; out[b*T*MAN + t*MAN + col], fp32);
//        3 = fused LSTM cell (gate-permuted cols; updates cstate fp32, writes hout bf16).
// AMODE: 0 = none; 1 = fp32 addmat[row*N+col]; 2 = bf16 addmat[row*N+col];
//        3 = fp32 addmat[gate_perm(row)*N+col];
//        4 = bf16 (row<B_ ? addmat : addmat2)[(row&1023)*N+col].
template<int SMODE, int AMODE>
__global__ __launch_bounds__(256, 2)
void gemm_bt(const unsigned short* __restrict__ A1, long lda1,
             const unsigned short* __restrict__ A2, long lda2, int K1,
             const unsigned short* __restrict__ W1, const unsigned short* __restrict__ W2,
             int N, int K,
             const float* __restrict__ bias,
             const void* __restrict__ addmat, const void* __restrict__ addmat2,
             void* __restrict__ outp, long ldo,
             float* __restrict__ cstate, unsigned short* __restrict__ hout)
{
  __shared__ unsigned short As[128 * 64];
  __shared__ unsigned short Bs[128 * 64];
  const int tid = threadIdx.x, lane = tid & 63, wave = tid >> 6;
  const long bm = blockIdx.x, bn = blockIdx.y;

  f32x4 acc[4][4] = {};

  const int nkt = K >> 6;
  const int wm = wave >> 1, wn = wave & 1;
  const int lr = lane & 15, lq = lane >> 4;

  for (int kt = 0; kt < nkt; ++kt) {
    const int k0 = kt << 6;
    const unsigned short* Ab; long lda; const unsigned short* Wb; long ldw; int ko;
    if (k0 < K1) { Ab = A1; lda = lda1; Wb = W1; ldw = K1;      ko = k0; }
    else         { Ab = A2; lda = lda2; Wb = W2; ldw = K - K1;  ko = k0 - K1; }
    __syncthreads();
    #pragma unroll
    for (int it = 0; it < 4; ++it) {
      const int c0 = it * 256 + wave * 64;
      const int c = c0 + lane;
      const int row = c >> 3, sub = c & 7;
      gload16(Ab + (bm * 128 + row) * lda + ko + sub * 8, &As[c0 * 8]);
      gload16(Wb + (bn * 128 + row) * ldw + ko + sub * 8, &Bs[c0 * 8]);
    }
    __syncthreads();
    #pragma unroll
    for (int kk = 0; kk < 2; ++kk) {
      short8 av[4], bv[4];
      const int lk = kk * 32 + lq * 8;
      #pragma unroll
      for (int m = 0; m < 4; ++m)
        av[m] = *reinterpret_cast<const short8*>(&As[(wm * 64 + m * 16 + lr) * 64 + lk]);
      #pragma unroll
      for (int n = 0; n < 4; ++n)
        bv[n] = *reinterpret_cast<const short8*>(&Bs[(wn * 64 + n * 16 + lr) * 64 + lk]);
      #pragma unroll
      for (int m = 0; m < 4; ++m)
        #pragma unroll
        for (int n = 0; n < 4; ++n)
          acc[m][n] = __builtin_amdgcn_mfma_f32_16x16x32_bf16(av[m], bv[n], acc[m][n], 0, 0, 0);
    }
  }

  if constexpr (SMODE == 3) {
    // fused LSTM cell: thread's n=0..3 fragments are i,f,g,o for h = bn*32+wn*16+lr
    const int hcol = (int)bn * 32 + wn * 16 + lr;
    const long colbase = bn * 128 + wn * 64 + lr;
    #pragma unroll
    for (int m = 0; m < 4; ++m) {
      #pragma unroll
      for (int r2 = 0; r2 < 4; ++r2) {
        const long row = bm * 128 + wm * 64 + m * 16 + lq * 4 + r2;
        float gi = acc[m][0][r2], gf = acc[m][1][r2], gg = acc[m][2][r2], go = acc[m][3][r2];
        const unsigned short* am = (const unsigned short*)addmat;
        const long ab = row * (long)N + colbase;
        gi += b2f(am[ab]);
        gf += b2f(am[ab + 16]);
        gg += b2f(am[ab + 32]);
        go += b2f(am[ab + 48]);
        const long ci = row * HID_ + hcol;
        float c = cstate[ci];
        c = sigmoidf_(gf) * c + sigmoidf_(gi) * tanh_fast(gg);
        cstate[ci] = c;
        hout[ci] = f2b(sigmoidf_(go) * tanh_fast(c));
      }
    }
    return;
  }

  // standard epilogues
  #pragma unroll
  for (int m = 0; m < 4; ++m) {
    #pragma unroll
    for (int n = 0; n < 4; ++n) {
      const long col = bn * 128 + wn * 64 + n * 16 + lr;
      const float bvv = bias ? bias[col] : 0.0f;
      #pragma unroll
      for (int r2 = 0; r2 < 4; ++r2) {
        const long row = bm * 128 + wm * 64 + m * 16 + lq * 4 + r2;
        float v = acc[m][n][r2] + bvv;
        if constexpr (AMODE == 1) v += ((const float*)addmat)[row * (long)N + col];
        if constexpr (AMODE == 2) v += b2f(((const unsigned short*)addmat)[row * (long)N + col]);
        if constexpr (AMODE == 3) v += ((const float*)addmat)[(long)gate_perm((int)row) * N + col];
        if constexpr (AMODE == 4)
          v += b2f(((const unsigned short*)(row < B_ ? addmat : addmat2))[(row & (B_ - 1)) * (long)N + col]);
        if constexpr (SMODE == 0) {
          reinterpret_cast<float*>(outp)[row * ldo + col] = v;
        } else if constexpr (SMODE == 1) {
          reinterpret_cast<unsigned short*>(outp)[row * ldo + col] = f2b(v);
        } else {
          const long bb = row & 1023, tt = (row >> 10) + 1;
          reinterpret_cast<float*>(outp)[bb * (T_ * MAN_) + tt * MAN_ + col] = v;
        }
      }
    }
  }
}

// ---------------- launcher ----------------
extern "C" void kernel_launch(void* const* d_in, const int* in_sizes, int n_in,
                              void* d_out, int out_size, void* d_ws, size_t ws_size,
                              hipStream_t stream) {
  const float* input_repr = (const float*)d_in[0];
  const float* time_enc   = (const float*)d_in[1];
  const float* y0         = (const float*)d_in[2];
  const float* W_ih       = (const float*)d_in[3];
  const float* b_ih       = (const float*)d_in[4];
  const float* W_hh       = (const float*)d_in[5];
  const float* b_hh       = (const float*)d_in[6];
  const float* W_mu       = (const float*)d_in[7];
  const float* b_mu       = (const float*)d_in[8];
  float* out = (float*)d_out;

  char* ws = (char*)d_ws;
  auto alloc = [&](size_t bytes) {
    char* p = ws; ws += (bytes + 255) & ~(size_t)255; return p;
  };
  unsigned short* Xtm    = (unsigned short*)alloc((size_t)T_ * B_ * FEAT_ * 2);   // 134 MB (time-major)
  unsigned short* hstore = (unsigned short*)alloc((size_t)T_ * B_ * HID_ * 2);    // 268 MB
  float*  cst   = (float*)alloc((size_t)B_ * HID_ * 4);                           // 8.4 MB
  unsigned short* TB2 = (unsigned short*)alloc((size_t)B_ * NG_ * 2);             // 16.8 MB (bf16, perm cols)
  unsigned short* TB1 = (unsigned short*)alloc((size_t)B_ * NG_ * 2);             // 16.8 MB
  unsigned short* Whhf  = (unsigned short*)alloc((size_t)NG_ * HID_ * 2);         // 33.5 MB (perm rows)
  unsigned short* Wxbf  = (unsigned short*)alloc((size_t)NG_ * FEAT_ * 2);        // 16.8 MB (perm rows)
  unsigned short* Wybf  = (unsigned short*)alloc((size_t)NG_ * MAN_ * 2);         // (perm rows)
  unsigned short* Wtebf = (unsigned short*)alloc((size_t)NG_ * TENC_ * 2);        // (perm rows)
  unsigned short* WmuT  = (unsigned short*)alloc((size_t)HID_ * MAN_ * 2);
  unsigned short* Wmubf = (unsigned short*)alloc((size_t)MAN_ * HID_ * 2);
  unsigned short* tebf  = (unsigned short*)alloc((size_t)B_ * TENC_ * 2);
  unsigned short* y0bf  = (unsigned short*)alloc((size_t)B_ * MAN_ * 2);
  float* bvec2 = (float*)alloc(NG_ * 4);
  float* nbm   = (float*)alloc(NG_ * 4);
  size_t base_bytes = (size_t)(ws - (char*)d_ws);
  // xg chunk buffer: CHUNK_ slabs of B_*NG_ bf16 (352 MB)
  size_t xg_bytes = (size_t)CHUNK_ * B_ * NG_ * 2;
  bool use_xg = (base_bytes + xg_bytes + 4096) <= ws_size;
  unsigned short* xg = use_xg ? (unsigned short*)alloc(xg_bytes) : nullptr;

  // --- conversions / preps (all parallel work) ---
  pack_x_tm<<<B_ * T_, 256, 0, stream>>>(input_repr, Xtm);
  pack_wih<<<dim3(2, NG_), 256, 0, stream>>>(W_ih, Wxbf, Wybf, Wtebf);
  pack_bf16<<<dim3(2, MAN_), 256, 0, stream>>>(W_mu, HID_, 0, Wmubf, HID_);
  pack_bf16<<<dim3(1, B_), 256, 0, stream>>>(time_enc, TENC_, 0, tebf, TENC_);
  pack_bf16<<<dim3(1, B_), 256, 0, stream>>>(y0, MAN_, 0, y0bf, MAN_);
  transpose_to_bf16<<<1024, 256, 0, stream>>>(W_mu, WmuT);
  bias_prep<<<NG_ / 256, 256, 0, stream>>>(W_ih, b_ih, b_hh, b_mu, bvec2, nbm);
  zero_u32<<<(B_ * HID_ / 2 + 255) / 256, 256, 0, stream>>>((unsigned int*)hstore, (long)B_ * HID_ / 2); // h0 = 0
  zero_u32<<<(B_ * HID_ + 255) / 256, 256, 0, stream>>>((unsigned int*)cst, (long)B_ * HID_);            // c0 = 0
  out_t0<<<B_ * MAN_ / 256, 256, 0, stream>>>(y0, out);

  // Whhf = perm(W_hh) + permWy @ W_mu   (bf16, rows permuted)   M=NG_, N=HID_, K=MAN_
  gemm_bt<1, 3><<<dim3(NG_ / 128, HID_ / 128), 256, 0, stream>>>(
      Wybf, MAN_, Wybf, MAN_, MAN_, WmuT, WmuT, HID_, MAN_,
      nullptr, W_hh, nullptr, Whhf, HID_, nullptr, nullptr);
  // TB2 = te @ permWte^T + permuted(b_ih + b_hh + b_mu@Wy^T)    M=B_, N=NG_, K=TENC_ (bf16 out)
  gemm_bt<1, 0><<<dim3(B_ / 128, NG_ / 128), 256, 0, stream>>>(
      tebf, TENC_, tebf, TENC_, TENC_, Wtebf, Wtebf, NG_, TENC_,
      bvec2, nullptr, nullptr, TB2, NG_, nullptr, nullptr);
  // TB1 = y0 @ permWy^T + TB2 - permuted(b_mu@Wy^T)             M=B_, N=NG_, K=MAN_ (bf16 out)
  gemm_bt<1, 2><<<dim3(B_ / 128, NG_ / 128), 256, 0, stream>>>(
      y0bf, MAN_, y0bf, MAN_, MAN_, Wybf, Wybf, NG_, MAN_,
      nbm, TB2, nullptr, TB1, NG_, nullptr, nullptr);

  if (use_xg) {
    // --- recurrence in 3 chunks: xg precompute (K=1024, parallel over 21·B rows),
    //     then 21 sequential steps of K=2048 h-GEMM + fused cell ---
    for (int c = 0; c < 3; ++c) {
      const int t0 = 1 + c * CHUNK_;
      // xg[tt] = x_{t0+tt} @ permWx^T + (t==1 ? TB1 : TB2)   (bf16, perm cols)
      gemm_bt<1, 4><<<dim3(CHUNK_ * B_ / 128, NG_ / 128), 256, 0, stream>>>(
          Xtm + (long)t0 * B_ * FEAT_, FEAT_, Xtm, FEAT_, 1024,
          Wxbf, Wxbf, NG_, 1024,
          nullptr, (c == 0 ? TB1 : TB2), TB2, xg, NG_, nullptr, nullptr);
      for (int t = t0; t < t0 + CHUNK_; ++t) {
        const unsigned short* A2 = hstore + (long)(t - 1) * B_ * HID_;  // h_{t-1}
        gemm_bt<3, 2><<<dim3(B_ / 128, NG_ / 128), 256, 0, stream>>>(
            A2, HID_, A2, HID_, HID_,
            Whhf, Whhf, NG_, HID_,
            nullptr, xg + (long)(t - t0) * B_ * NG_, nullptr, nullptr, 0,
            cst, hstore + (long)t * B_ * HID_);
      }
    }
  } else {
    // fallback (R2-proven path): per-step K=3072 two-region GEMM + fused cell
    for (int t = 1; t < T_; ++t) {
      const unsigned short* A1 = Xtm + (long)t * B_ * FEAT_;
      const unsigned short* A2 = hstore + (long)(t - 1) * B_ * HID_;
      gemm_bt<3, 2><<<dim3(B_ / 128, NG_ / 128), 256, 0, stream>>>(
          A1, FEAT_, A2, HID_, FEAT_,
          Wxbf, Whhf, NG_, FEAT_ + HID_,
          nullptr, (t == 1 ? TB1 : TB2), nullptr, nullptr, 0,
          cst, hstore + (long)t * B_ * HID_);
    }
  }

  // --- all outputs y_t = h_t @ W_mu^T + b_mu in one GEMM, scattered into (B,T,MAN) ---
  gemm_bt<2, 0><<<dim3((T_ - 1) * B_ / 128, MAN_ / 128), 256, 0, stream>>>(
      hstore + (long)B_ * HID_, HID_, hstore + (long)B_ * HID_, HID_, HID_,
      Wmubf, Wmubf, MAN_, HID_,
      b_mu, nullptr, nullptr, out, 0, nullptr, nullptr);
}